// Round 4
// baseline (54.380 us; speedup 1.0000x reference)
//
#include <hip/hip_runtime.h>

#define EPSF 1e-20f

constexpr int Hh = 768, Ww = 768, Bb = 4;
constexpr int PLANE = Hh * Ww;
constexpr int TS = 32;         // output tile
constexpr int R3 = TS + 6;     // 38: halo-3 region (d, dq, c)
constexpr int R2 = TS + 4;     // 36: halo-2 region (stage-1 outputs tc, ts)
constexpr int R1 = TS + 2;     // 34: halo-1 region (conv outputs / s)

// ---- fused: stage 1 (argmax/gather/pow/blend) + stage 2 (conv) + stage 3 ----
__global__ __launch_bounds__(256)
void fused_all(const float* __restrict__ x, const float* __restrict__ scs,
               const float* __restrict__ cs,
               const float* __restrict__ w_sp_d, const float* __restrict__ w_sp_s,
               const float* __restrict__ w_pow_s, const float* __restrict__ w_prop_s,
               float* __restrict__ out) {
    __shared__ float s_d[R3][R3 + 1];   // raw dcd
    __shared__ float s_q[R3][R3 + 1];   // dq = d/(c+eps), precise
    __shared__ float s_c[R3][R3 + 1];   // raw cd
    __shared__ float s_tc[R2][R2 + 1];  // stage-1 blended conv input (cs path)
    __shared__ float s_ts[R2][R2 + 1];  // stage-1 blended conv input (scs path)
    __shared__ float s_s[R1][R1 + 1];   // s = scs_out/(cs_out+eps), 0 outside image
    __shared__ float sw[20];            // wd[0..8], ws[9..17], wps, wpow at 18,19

    const int b = blockIdx.z;
    const int ty0 = blockIdx.y * TS, tx0 = blockIdx.x * TS;
    const int tid = threadIdx.x;
    const float* dcd = x + b * PLANE;
    const float* cd  = x + (Bb + b) * PLANE;

    if (tid == 0) {   // inline weight prep
        float sd[9], ss[9], sum_d = 0.f, sum_s = 0.f;
        for (int r = 0; r < 3; ++r)
            for (int c = 0; c < 3; ++c) {
                int cc = (c == 2) ? 0 : c;      // mirrored 3rd column
                float vd = log1pf(expf(w_sp_d[r * 2 + cc]));
                float vs = log1pf(expf(w_sp_s[r * 2 + cc]));
                sd[r * 3 + c] = vd; ss[r * 3 + c] = vs;
                sum_d += vd; sum_s += vs;
            }
        for (int k = 0; k < 9; ++k) { sw[k] = sd[k] / sum_d; sw[9 + k] = ss[k] / sum_s; }
        sw[18] = 1.f / (1.f + expf(-w_prop_s[0]));   // wps
        sw[19] = log1pf(expf(w_pow_s[0]));           // wpow
    }

    // ---- Phase A: load d/c at halo-3, precompute dq once per pixel ----
    for (int i = tid; i < R3 * R3; i += 256) {
        int ly = i / R3, lx = i - ly * R3;
        int gy = ty0 - 3 + ly, gx = tx0 - 3 + lx;
        float vd = 0.f, vc = 0.f;
        if ((unsigned)gy < (unsigned)Hh && (unsigned)gx < (unsigned)Ww) {
            vd = dcd[gy * Ww + gx];
            vc = cd[gy * Ww + gx];
        }
        s_d[ly][lx] = vd;
        s_q[ly][lx] = vd / (vc + EPSF);
        s_c[ly][lx] = vc;
    }
    __syncthreads();

    const float wps  = sw[18];
    const float wpow = sw[19];

    // ---- Phase B: stage 1 on halo-2 region ----
    for (int i = tid; i < R2 * R2; i += 256) {
        int ly = i / R2, lx = i - ly * R2;          // offset +1 into R3 arrays
        int gy = ty0 - 2 + ly, gx = tx0 - 2 + lx;
        float tc = 0.f, ts = 0.f;
        if ((unsigned)gy < (unsigned)Hh && (unsigned)gx < (unsigned)Ww) {
            float dq0 = s_q[ly][lx], vc0 = s_c[ly][lx];
            float amax = dq0 * vc0;
            float dmax = dq0, cmax = vc0;           // gathered at j_max
            float dqeB = dq0 + EPSF;                // (d_jmin + eps)
            float vcB  = vc0;                       // cd_jmin
            #pragma unroll
            for (int k = 1; k < 9; ++k) {
                float dq = s_q[ly + k / 3][lx + k % 3];
                float vc = s_c[ly + k / 3][lx + k % 3];
                float aq = dq * vc;
                bool m1 = aq > amax;
                amax = m1 ? aq : amax;
                dmax = m1 ? dq : dmax;
                cmax = m1 ? vc : cmax;
                float dqe = dq + EPSF;
                bool m2 = (vc * dqeB) > (vcB * dqe);   // vc/dqe > vcB/dqeB
                dqeB = m2 ? dqe : dqeB;
                vcB  = m2 ? vc  : vcB;
            }
            float s_new = __builtin_amdgcn_exp2f(
                wpow * (__builtin_amdgcn_logf(dqeB) - __builtin_amdgcn_logf(dmax + EPSF)));
            float cs_new = cmax * vcB;
            int idx = gy * Ww + gx;
            float csv  = cs[b * PLANE + idx];
            float scsv = scs[b * PLANE + idx];
            tc = csv * wps + cs_new * (1.f - wps);
            ts = scsv * wps + s_new * cs_new * (1.f - wps);
        }
        s_tc[ly][lx] = tc; s_ts[ly][lx] = ts;
    }
    __syncthreads();

    float wk[9];
    #pragma unroll
    for (int k = 0; k < 9; ++k) wk[k] = sw[9 + k];

    // ---- Phase C: stage 2 conv on halo-1 region; write interior, keep s ----
    // NOTE: reference pads s with ZEROS outside the image (_pad1(s)), so s_s
    // must be 0 at out-of-image halo positions, NOT the computed conv value.
    for (int i = tid; i < R1 * R1; i += 256) {
        int ly = i / R1, lx = i - ly * R1;          // offset +1 into R2 arrays
        int gy = ty0 - 1 + ly, gx = tx0 - 1 + lx;
        float accC = 0.f, accS = 0.f;
        #pragma unroll
        for (int k = 0; k < 9; ++k) {
            accC += wk[k] * s_tc[ly + k / 3][lx + k % 3];
            accS += wk[k] * s_ts[ly + k / 3][lx + k % 3];
        }
        bool in_img = (unsigned)gy < (unsigned)Hh && (unsigned)gx < (unsigned)Ww;
        s_s[ly][lx] = in_img ? (accS * __builtin_amdgcn_rcpf(accC + EPSF)) : 0.f;
        // interior of this tile -> global outputs (scs_out planes 8.., cs_out 12..)
        int iy = ly - 1, ix = lx - 1;
        if ((unsigned)iy < (unsigned)TS && (unsigned)ix < (unsigned)TS) {
            int idx = (ty0 + iy) * Ww + (tx0 + ix);
            out[(8 + b)  * PLANE + idx] = accS;
            out[(12 + b) * PLANE + idx] = accC;
        }
    }
    __syncthreads();

    float wd[9];
    #pragma unroll
    for (int k = 0; k < 9; ++k) wd[k] = sw[k];

    // ---- Phase D: stage 3 on interior ----
    for (int i = tid; i < TS * TS; i += 256) {
        int ly = i / TS, lx = i - ly * TS;
        // s_s: interior pixel (ly,lx) is s_s[ly+1][lx+1]; taps at [ly+ky][lx+kx]
        // s_d/s_c: interior pixel is s_d[ly+3][lx+3]; taps at [ly+2+ky][lx+2+kx]
        float sc = s_s[ly + 1][lx + 1];
        float nd = 0.f, nc = 0.f, den = 0.f;
        #pragma unroll
        for (int k = 0; k < 9; ++k) {
            int ky = k / 3, kx = k % 3;
            float wsk = (k == 4) ? 1.f : (s_s[ly + ky][lx + kx] * sc);
            float w = wd[k] * wsk;
            nd  += w * s_d[ly + 2 + ky][lx + 2 + kx];
            nc  += w * s_c[ly + 2 + ky][lx + 2 + kx];
            den += w;
        }
        float rinv = __builtin_amdgcn_rcpf(den + EPSF);
        int idx = (ty0 + ly) * Ww + (tx0 + lx);
        out[(2 * b)     * PLANE + idx] = nd * rinv;
        out[(2 * b + 1) * PLANE + idx] = nc * rinv;
    }
}

extern "C" void kernel_launch(void* const* d_in, const int* in_sizes, int n_in,
                              void* d_out, int out_size, void* d_ws, size_t ws_size,
                              hipStream_t stream) {
    const float* x        = (const float*)d_in[0];
    const float* scs      = (const float*)d_in[1];
    const float* cs       = (const float*)d_in[2];
    // d_in[3] = w_channel_d (1,1) -> normalizes to 1, unused
    const float* w_sp_d   = (const float*)d_in[4];
    const float* w_pow_s  = (const float*)d_in[5];
    const float* w_prop_s = (const float*)d_in[6];
    // d_in[7] = w_channel_s (1,1) -> normalizes to 1, unused
    const float* w_sp_s   = (const float*)d_in[8];
    float* out  = (float*)d_out;

    dim3 grid(Ww / TS, Hh / TS, Bb);   // 24 x 24 x 4
    fused_all<<<grid, 256, 0, stream>>>(x, scs, cs, w_sp_d, w_sp_s, w_pow_s, w_prop_s, out);
}

// Round 5
// 43.006 us; speedup vs baseline: 1.2645x; 1.2645x over previous
//
#include <hip/hip_runtime.h>

#define EPSF 1e-20f

constexpr int Hh = 768, Ww = 768, Bb = 4;
constexpr int PLANE = Hh * Ww;
constexpr int TS = 32;         // output tile
constexpr int R3 = TS + 6;     // 38: halo-3 region (dq, c)
constexpr int R2 = TS + 4;     // 36: halo-2 region (tc, ts)
constexpr int R1 = TS + 2;     // 34: halo-1 region (s)

// ---- fused: stage 1 (argmax/gather/pow/blend) + stage 2 (conv) + stage 3 ----
__global__ __launch_bounds__(256)
void fused_all(const float* __restrict__ x, const float* __restrict__ scs,
               const float* __restrict__ cs,
               const float* __restrict__ w_sp_d, const float* __restrict__ w_sp_s,
               const float* __restrict__ w_pow_s, const float* __restrict__ w_prop_s,
               float* __restrict__ out) {
    __shared__ float2 s_qc[R3][R3];   // (.x = dq = d/(c+eps), .y = c)   11552 B
    __shared__ float2 s_t[R2][R2];    // (.x = tc, .y = ts)              10368 B
    __shared__ float  s_s[R1][R1];    // s, 0 outside image               4624 B
    __shared__ float  sw[20];         // wd[0..8], ws[9..17], wps, wpow

    const int b = blockIdx.z;
    const int ty0 = blockIdx.y * TS, tx0 = blockIdx.x * TS;
    const int tid = threadIdx.x;
    const float* dcd = x + b * PLANE;
    const float* cd  = x + (Bb + b) * PLANE;

    if (tid == 0) {   // inline weight prep
        float sd[9], ss[9], sum_d = 0.f, sum_s = 0.f;
        for (int r = 0; r < 3; ++r)
            for (int c = 0; c < 3; ++c) {
                int cc = (c == 2) ? 0 : c;      // mirrored 3rd column
                float vd = log1pf(expf(w_sp_d[r * 2 + cc]));
                float vs = log1pf(expf(w_sp_s[r * 2 + cc]));
                sd[r * 3 + c] = vd; ss[r * 3 + c] = vs;
                sum_d += vd; sum_s += vs;
            }
        for (int k = 0; k < 9; ++k) { sw[k] = sd[k] / sum_d; sw[9 + k] = ss[k] / sum_s; }
        sw[18] = 1.f / (1.f + expf(-w_prop_s[0]));   // wps
        sw[19] = log1pf(expf(w_pow_s[0]));           // wpow
    }

    // ---- Phase A: load d/c at halo-3, precompute dq once; store paired ----
    for (int i = tid; i < R3 * R3; i += 256) {
        int ly = i / R3, lx = i - ly * R3;
        int gy = ty0 - 3 + ly, gx = tx0 - 3 + lx;
        float vd = 0.f, vc = 0.f;
        if ((unsigned)gy < (unsigned)Hh && (unsigned)gx < (unsigned)Ww) {
            vd = dcd[gy * Ww + gx];
            vc = cd[gy * Ww + gx];
        }
        s_qc[ly][lx] = make_float2(vd / (vc + EPSF), vc);
    }
    __syncthreads();

    const float wps  = sw[18];
    const float wpow = sw[19];
    const float onemw = 1.f - wps;

    // ---- Phase B: stage 1 on halo-2 region (paired b64 taps) ----
    for (int i = tid; i < R2 * R2; i += 256) {
        int ly = i / R2, lx = i - ly * R2;          // offset +1 into R3 array
        int gy = ty0 - 2 + ly, gx = tx0 - 2 + lx;
        float tc = 0.f, ts = 0.f;
        if ((unsigned)gy < (unsigned)Hh && (unsigned)gx < (unsigned)Ww) {
            float2 q0 = s_qc[ly][lx];
            float amax = q0.x * q0.y;               // dp*cp, k=0
            float dmax = q0.x, cmax = q0.y;         // gathered at j_max
            float dqeB = q0.x + EPSF;               // (d_jmin + eps)
            float vcB  = q0.y;                      // cd_jmin
            #pragma unroll
            for (int k = 1; k < 9; ++k) {
                float2 q = s_qc[ly + k / 3][lx + k % 3];
                float aq = q.x * q.y;
                bool m1 = aq > amax;
                amax = m1 ? aq : amax;
                dmax = m1 ? q.x : dmax;
                cmax = m1 ? q.y : cmax;
                float dqe = q.x + EPSF;
                bool m2 = (q.y * dqeB) > (vcB * dqe);   // q.y/dqe > vcB/dqeB
                dqeB = m2 ? dqe : dqeB;
                vcB  = m2 ? q.y : vcB;
            }
            float s_new = __builtin_amdgcn_exp2f(
                wpow * (__builtin_amdgcn_logf(dqeB) - __builtin_amdgcn_logf(dmax + EPSF)));
            float cs_new = cmax * vcB;
            int idx = gy * Ww + gx;
            tc = cs[b * PLANE + idx]  * wps + cs_new * onemw;
            ts = scs[b * PLANE + idx] * wps + s_new * cs_new * onemw;
        }
        s_t[ly][lx] = make_float2(tc, ts);
    }
    __syncthreads();

    float wk[9];
    #pragma unroll
    for (int k = 0; k < 9; ++k) wk[k] = sw[9 + k];

    // ---- Phase C: stage 2 conv on halo-1; write interior, keep s in LDS ----
    // Reference pads s with ZEROS outside the image, so s_s=0 there.
    for (int i = tid; i < R1 * R1; i += 256) {
        int ly = i / R1, lx = i - ly * R1;          // offset +1 into R2 array
        int gy = ty0 - 1 + ly, gx = tx0 - 1 + lx;
        float accC = 0.f, accS = 0.f;
        #pragma unroll
        for (int k = 0; k < 9; ++k) {
            float2 t = s_t[ly + k / 3][lx + k % 3];
            accC += wk[k] * t.x;
            accS += wk[k] * t.y;
        }
        bool in_img = (unsigned)gy < (unsigned)Hh && (unsigned)gx < (unsigned)Ww;
        s_s[ly][lx] = in_img ? (accS * __builtin_amdgcn_rcpf(accC + EPSF)) : 0.f;
        int iy = ly - 1, ix = lx - 1;
        if ((unsigned)iy < (unsigned)TS && (unsigned)ix < (unsigned)TS) {
            int idx = (ty0 + iy) * Ww + (tx0 + ix);
            out[(8 + b)  * PLANE + idx] = accS;
            out[(12 + b) * PLANE + idx] = accC;
        }
    }
    __syncthreads();

    float wd[9];
    #pragma unroll
    for (int k = 0; k < 9; ++k) wd[k] = sw[k];

    // ---- Phase D: stage 3 on interior (d reconstructed as dq*(c+eps)) ----
    for (int i = tid; i < TS * TS; i += 256) {
        int ly = i >> 5, lx = i & 31;
        // s_s: interior px (ly,lx) center at [ly+1][lx+1]; taps [ly+ky][lx+kx]
        // s_qc: interior px at [ly+3][lx+3]; taps [ly+2+ky][lx+2+kx]
        float sc = s_s[ly + 1][lx + 1];
        float nd = 0.f, nc = 0.f, den = 0.f;
        #pragma unroll
        for (int k = 0; k < 9; ++k) {
            int ky = k / 3, kx = k % 3;
            float wsk = (k == 4) ? 1.f : (s_s[ly + ky][lx + kx] * sc);
            float w = wd[k] * wsk;
            float2 q = s_qc[ly + 2 + ky][lx + 2 + kx];
            nd  += w * (q.x * (q.y + EPSF));   // d = dq*(c+eps), rel err ~1e-7
            nc  += w * q.y;
            den += w;
        }
        float rinv = __builtin_amdgcn_rcpf(den + EPSF);
        int idx = (ty0 + ly) * Ww + (tx0 + lx);
        out[(2 * b)     * PLANE + idx] = nd * rinv;
        out[(2 * b + 1) * PLANE + idx] = nc * rinv;
    }
}

extern "C" void kernel_launch(void* const* d_in, const int* in_sizes, int n_in,
                              void* d_out, int out_size, void* d_ws, size_t ws_size,
                              hipStream_t stream) {
    const float* x        = (const float*)d_in[0];
    const float* scs      = (const float*)d_in[1];
    const float* cs       = (const float*)d_in[2];
    // d_in[3] = w_channel_d (1,1) -> normalizes to 1, unused
    const float* w_sp_d   = (const float*)d_in[4];
    const float* w_pow_s  = (const float*)d_in[5];
    const float* w_prop_s = (const float*)d_in[6];
    // d_in[7] = w_channel_s (1,1) -> normalizes to 1, unused
    const float* w_sp_s   = (const float*)d_in[8];
    float* out  = (float*)d_out;

    dim3 grid(Ww / TS, Hh / TS, Bb);   // 24 x 24 x 4
    fused_all<<<grid, 256, 0, stream>>>(x, scs, cs, w_sp_d, w_sp_s, w_pow_s, w_prop_s, out);
}

// Round 6
// 41.523 us; speedup vs baseline: 1.3096x; 1.0357x over previous
//
#include <hip/hip_runtime.h>

#define EPSF 1e-20f

constexpr int Hh = 768, Ww = 768, Bb = 4;
constexpr int PLANE = Hh * Ww;
constexpr int TS = 32;         // output tile
constexpr int R3 = TS + 6;     // 38: halo-3 (dq, c)
constexpr int R2 = TS + 4;     // 36: halo-2 (tc, ts)
constexpr int R1 = TS + 2;     // 34: halo-1 (s)

// fused: stage 1 (hierarchical argmax/gather/pow/blend) + stage 2 (conv) + stage 3
__global__ __launch_bounds__(256)
void fused_all(const float* __restrict__ x, const float* __restrict__ scs,
               const float* __restrict__ cs,
               const float* __restrict__ w_sp_d, const float* __restrict__ w_sp_s,
               const float* __restrict__ w_pow_s, const float* __restrict__ w_prop_s,
               float* __restrict__ out) {
    __shared__ float2 s_qc[R3][R3];   // (.x = dq = d/(c+eps), .y = c)
    __shared__ float2 s_t[R2][R2];    // (.x = tc, .y = ts)
    __shared__ float  s_s[R1][R1];    // s, 0 outside image
    __shared__ float  sw[20];         // wd[0..8], ws[9..17], wps, wpow

    const int b = blockIdx.z;
    const int ty0 = blockIdx.y * TS, tx0 = blockIdx.x * TS;
    const int tid = threadIdx.x;
    const float* dcd = x + b * PLANE;
    const float* cd  = x + (Bb + b) * PLANE;

    if (tid == 0) {   // inline weight prep
        float sd[9], ss[9], sum_d = 0.f, sum_s = 0.f;
        for (int r = 0; r < 3; ++r)
            for (int c = 0; c < 3; ++c) {
                int cc = (c == 2) ? 0 : c;      // mirrored 3rd column
                float vd = log1pf(expf(w_sp_d[r * 2 + cc]));
                float vs = log1pf(expf(w_sp_s[r * 2 + cc]));
                sd[r * 3 + c] = vd; ss[r * 3 + c] = vs;
                sum_d += vd; sum_s += vs;
            }
        for (int k = 0; k < 9; ++k) { sw[k] = sd[k] / sum_d; sw[9 + k] = ss[k] / sum_s; }
        sw[18] = 1.f / (1.f + expf(-w_prop_s[0]));   // wps
        sw[19] = log1pf(expf(w_pow_s[0]));           // wpow
    }

    // ---- Phase A: load d/c at halo-3, precompute dq once; store paired ----
    for (int i = tid; i < R3 * R3; i += 256) {
        int ly = i / R3, lx = i - ly * R3;
        int gy = ty0 - 3 + ly, gx = tx0 - 3 + lx;
        float vd = 0.f, vc = 0.f;
        if ((unsigned)gy < (unsigned)Hh && (unsigned)gx < (unsigned)Ww) {
            vd = dcd[gy * Ww + gx];
            vc = cd[gy * Ww + gx];
        }
        s_qc[ly][lx] = make_float2(vd / (vc + EPSF), vc);
    }
    __syncthreads();

    const float wps  = sw[18];
    const float wpow = sw[19];
    const float onemw = 1.f - wps;

    // ---- Phase B: stage 1, column sweep: 36 cols x 6 groups of 6 rows ----
    // Hierarchical first-wins argmax: row-max over dx (k-minor), combine over
    // dy (k-major) — exactly reproduces jnp.argmax first-occurrence order.
    {
        const int xB = tid % R2;          // 0..35
        const int tyB = tid / R2;         // 0..7; active < 6 (216 threads)
        if (tyB < 6) {
            const int yb0 = tyB * 6;
            float ma[3], md[3], mc[3];    // jmax row-partials (key, dq, c)
            float nv[3], nq[3];           // jmin row-partials (vc, dq+eps)
#define HROW_B(rr, slot) { \
            float2 q0 = s_qc[rr][xB]; float2 q1 = s_qc[rr][xB + 1]; float2 q2 = s_qc[rr][xB + 2]; \
            float a0 = q0.x * q0.y, a1 = q1.x * q1.y, a2 = q2.x * q2.y; \
            float A = a0, D = q0.x, C = q0.y; \
            if (a1 > A) { A = a1; D = q1.x; C = q1.y; } \
            if (a2 > A) { A = a2; D = q2.x; C = q2.y; } \
            ma[slot] = A; md[slot] = D; mc[slot] = C; \
            float V = q0.y, Q = q0.x + EPSF; \
            float e1 = q1.x + EPSF, e2 = q2.x + EPSF; \
            if (q1.y * Q > V * e1) { V = q1.y; Q = e1; } \
            if (q2.y * Q > V * e2) { V = q2.y; Q = e2; } \
            nv[slot] = V; nq[slot] = Q; }
            HROW_B(yb0 + 0, 0)
            HROW_B(yb0 + 1, 1)
            #pragma unroll
            for (int j = 0; j < 6; ++j) {
                const int sl2 = (j + 2) % 3, s0 = j % 3, s1 = (j + 1) % 3;
                HROW_B(yb0 + j + 2, sl2)
                float A = ma[s0], D = md[s0], C = mc[s0];
                if (ma[s1]  > A) { A = ma[s1];  D = md[s1];  C = mc[s1];  }
                if (ma[sl2] > A) { A = ma[sl2]; D = md[sl2]; C = mc[sl2]; }
                float V = nv[s0], Q = nq[s0];
                if (nv[s1]  * Q > V * nq[s1])  { V = nv[s1];  Q = nq[s1];  }
                if (nv[sl2] * Q > V * nq[sl2]) { V = nv[sl2]; Q = nq[sl2]; }
                const int yb = yb0 + j;
                const int gy = ty0 - 2 + yb, gx = tx0 - 2 + xB;
                float tc = 0.f, ts = 0.f;
                if ((unsigned)gy < (unsigned)Hh && (unsigned)gx < (unsigned)Ww) {
                    float s_new = __builtin_amdgcn_exp2f(wpow *
                        (__builtin_amdgcn_logf(Q) - __builtin_amdgcn_logf(D + EPSF)));
                    float cs_new = C * V;
                    int idx = gy * Ww + gx;
                    tc = cs[b * PLANE + idx]  * wps + cs_new * onemw;
                    ts = scs[b * PLANE + idx] * wps + s_new * cs_new * onemw;
                }
                s_t[yb][xB] = make_float2(tc, ts);
            }
        }
    }
    __syncthreads();

    // ---- Phase C: stage 2 conv, column sweep: 34 cols x 7 groups of 5 ----
    // Kernel rows are (a,b,a) mirrored -> u = t[x-1]+t[x+1], 2 FMA per row/ch.
    {
        const int xC = tid % R1;          // 0..33
        const int tyC = tid / R1;         // 0..7; active < 7 (238 threads)
        const float wa0 = sw[9],  wb0 = sw[10];
        const float wa1 = sw[12], wb1 = sw[13];
        const float wa2 = sw[15], wb2 = sw[16];
        if (tyC < 7) {
            const int yc0 = tyC * 5;
            float2 u[3], tm[3];
#define HROW_C(rr, slot) { \
            float2 t0 = s_t[rr][xC]; float2 t1 = s_t[rr][xC + 1]; float2 t2 = s_t[rr][xC + 2]; \
            u[slot] = make_float2(t0.x + t2.x, t0.y + t2.y); tm[slot] = t1; }
            HROW_C(yc0 + 0, 0)
            HROW_C(yc0 + 1, 1)
            #pragma unroll
            for (int j = 0; j < 5; ++j) {
                const int yc = yc0 + j;
                if (yc < R1) {
                    const int sl2 = (j + 2) % 3, s0 = j % 3, s1 = (j + 1) % 3;
                    HROW_C(yc + 2, sl2)
                    float accC = wa0 * u[s0].x + wb0 * tm[s0].x
                               + wa1 * u[s1].x + wb1 * tm[s1].x
                               + wa2 * u[sl2].x + wb2 * tm[sl2].x;
                    float accS = wa0 * u[s0].y + wb0 * tm[s0].y
                               + wa1 * u[s1].y + wb1 * tm[s1].y
                               + wa2 * u[sl2].y + wb2 * tm[sl2].y;
                    const int gy = ty0 - 1 + yc, gx = tx0 - 1 + xC;
                    bool in_img = (unsigned)gy < (unsigned)Hh && (unsigned)gx < (unsigned)Ww;
                    s_s[yc][xC] = in_img ? (accS * __builtin_amdgcn_rcpf(accC + EPSF)) : 0.f;
                    const int iy = yc - 1, ix = xC - 1;
                    if ((unsigned)iy < (unsigned)TS && (unsigned)ix < (unsigned)TS) {
                        int idx = (ty0 + iy) * Ww + (tx0 + ix);
                        out[(8 + b)  * PLANE + idx] = accS;
                        out[(12 + b) * PLANE + idx] = accC;
                    }
                }
            }
        }
    }
    __syncthreads();

    // ---- Phase D: stage 3, column sweep: 32 cols x 8 groups of 4 rows ----
    {
        const int xD = tid & 31, tyD = tid >> 5;
        const int yd0 = tyD * 4;
        float wdk[9];
        #pragma unroll
        for (int k = 0; k < 9; ++k) wdk[k] = sw[k];
        float  srw[3][3];
        float2 qrw[3][3];
        // s-row rr maps to: s_s[rr][xD..xD+2], qc row rr+2 cols xD+2..xD+4
#define HROW_D(rr, slot) { \
        srw[slot][0] = s_s[rr][xD]; srw[slot][1] = s_s[rr][xD + 1]; srw[slot][2] = s_s[rr][xD + 2]; \
        qrw[slot][0] = s_qc[rr + 2][xD + 2]; qrw[slot][1] = s_qc[rr + 2][xD + 3]; qrw[slot][2] = s_qc[rr + 2][xD + 4]; }
        HROW_D(yd0 + 0, 0)
        HROW_D(yd0 + 1, 1)
#define TAP_D(slot, kk, cc2) { \
        float wsk = ((kk) == 4) ? 1.f : (srw[slot][cc2] * sc); \
        float w = wdk[kk] * wsk; \
        float2 q = qrw[slot][cc2]; \
        acc_d += w * (q.x * (q.y + EPSF)); \
        acc_c += w * q.y; \
        acc_w += w; }
        #pragma unroll
        for (int j = 0; j < 4; ++j) {
            const int sl2 = (j + 2) % 3, s0 = j % 3, s1 = (j + 1) % 3;
            HROW_D(yd0 + j + 2, sl2)
            float sc = srw[s1][1];
            float acc_d = 0.f, acc_c = 0.f, acc_w = 0.f;
            TAP_D(s0, 0, 0) TAP_D(s0, 1, 1) TAP_D(s0, 2, 2)
            TAP_D(s1, 3, 0) TAP_D(s1, 4, 1) TAP_D(s1, 5, 2)
            TAP_D(sl2, 6, 0) TAP_D(sl2, 7, 1) TAP_D(sl2, 8, 2)
            float rinv = __builtin_amdgcn_rcpf(acc_w + EPSF);
            int idx = (ty0 + yd0 + j) * Ww + (tx0 + xD);
            out[(2 * b)     * PLANE + idx] = acc_d * rinv;   // d = dq*(c+eps)
            out[(2 * b + 1) * PLANE + idx] = acc_c * rinv;
        }
    }
}

extern "C" void kernel_launch(void* const* d_in, const int* in_sizes, int n_in,
                              void* d_out, int out_size, void* d_ws, size_t ws_size,
                              hipStream_t stream) {
    const float* x        = (const float*)d_in[0];
    const float* scs      = (const float*)d_in[1];
    const float* cs       = (const float*)d_in[2];
    // d_in[3] = w_channel_d (1,1) -> normalizes to 1, unused
    const float* w_sp_d   = (const float*)d_in[4];
    const float* w_pow_s  = (const float*)d_in[5];
    const float* w_prop_s = (const float*)d_in[6];
    // d_in[7] = w_channel_s (1,1) -> normalizes to 1, unused
    const float* w_sp_s   = (const float*)d_in[8];
    float* out  = (float*)d_out;

    dim3 grid(Ww / TS, Hh / TS, Bb);   // 24 x 24 x 4
    fused_all<<<grid, 256, 0, stream>>>(x, scs, cs, w_sp_d, w_sp_s, w_pow_s, w_prop_s, out);
}

// Round 7
// 37.233 us; speedup vs baseline: 1.4605x; 1.1152x over previous
//
#include <hip/hip_runtime.h>

#define EPSF 1e-20f

constexpr int Hh = 768, Ww = 768, Bb = 4;
constexpr int PLANE = Hh * Ww;
constexpr int TS = 32;         // output tile
constexpr int R3 = TS + 6;     // 38: halo-3 (dq, c)
constexpr int R2 = TS + 4;     // 36: halo-2 (tc, ts) -> reused for conv outputs
constexpr int R1 = TS + 2;     // 34: halo-1 (s)

// fused: stage 1 (hierarchical argmax) + stage 2 (conv) + stage 3, latency-tuned
__global__ __launch_bounds__(256)
void fused_all(const float* __restrict__ x, const float* __restrict__ scs,
               const float* __restrict__ cs,
               const float* __restrict__ w_sp_d, const float* __restrict__ w_sp_s,
               const float* __restrict__ w_pow_s, const float* __restrict__ w_prop_s,
               float* __restrict__ out) {
    __shared__ float2 s_qc[R3][R3];   // (.x = dq = d/(c+eps), .y = c)
    __shared__ float2 s_t[R2][R2];    // phase B: (tc,ts); phase C2+: (accC,accS)
    __shared__ float  s_s[R1][R1];    // s, 0 outside image
    __shared__ float  sw[20];         // wd[0..8], ws[9..17], wps, wpow

    // XCD-bijective swizzle: 2304 blocks = 8 XCDs x 288; each XCD gets a
    // contiguous 12x24-tile half-batch -> halo re-reads hit its private L2.
    const int orig = blockIdx.x;
    const int swz  = (orig & 7) * 288 + (orig >> 3);
    const int b    = swz / 576;
    const int rem  = swz - b * 576;
    const int ty0  = (rem / 24) * TS;
    const int tx0  = (rem % 24) * TS;

    const int tid = threadIdx.x;
    const float* dcd = x + b * PLANE;
    const float* cd  = x + (Bb + b) * PLANE;

    if (tid == 0) {   // inline weight prep
        float sd[9], ss[9], sum_d = 0.f, sum_s = 0.f;
        for (int r = 0; r < 3; ++r)
            for (int c = 0; c < 3; ++c) {
                int cc = (c == 2) ? 0 : c;      // mirrored 3rd column
                float vd = log1pf(expf(w_sp_d[r * 2 + cc]));
                float vs = log1pf(expf(w_sp_s[r * 2 + cc]));
                sd[r * 3 + c] = vd; ss[r * 3 + c] = vs;
                sum_d += vd; sum_s += vs;
            }
        for (int k = 0; k < 9; ++k) { sw[k] = sd[k] / sum_d; sw[9 + k] = ss[k] / sum_s; }
        sw[18] = 1.f / (1.f + expf(-w_prop_s[0]));   // wps
        sw[19] = log1pf(expf(w_pow_s[0]));           // wpow
    }

    // ---- Phase A: vectorized load at halo-3; dq precomputed once ----
    // Row covers gx in [tx0-4, tx0+36): 10 aligned float4 segments; only
    // seg 0 (left edge tile) and seg 9 (right edge tile) can go OOB.
    for (int it = tid; it < R3 * 10; it += 256) {
        int row = it / 10, seg = it - row * 10;
        int gy = ty0 - 3 + row;
        int gxb = tx0 - 4 + seg * 4;
        float4 vd4 = make_float4(0.f, 0.f, 0.f, 0.f);
        float4 vc4 = vd4;
        if ((unsigned)gy < (unsigned)Hh) {
            bool safe = (seg > 0 && seg < 9) || (seg == 0 ? (tx0 > 0) : (tx0 + TS < Ww));
            if (safe) {
                vd4 = *(const float4*)(dcd + gy * Ww + gxb);
                vc4 = *(const float4*)(cd  + gy * Ww + gxb);
            } else {
                if ((unsigned)(gxb + 0) < (unsigned)Ww) { vd4.x = dcd[gy*Ww+gxb+0]; vc4.x = cd[gy*Ww+gxb+0]; }
                if ((unsigned)(gxb + 1) < (unsigned)Ww) { vd4.y = dcd[gy*Ww+gxb+1]; vc4.y = cd[gy*Ww+gxb+1]; }
                if ((unsigned)(gxb + 2) < (unsigned)Ww) { vd4.z = dcd[gy*Ww+gxb+2]; vc4.z = cd[gy*Ww+gxb+2]; }
                if ((unsigned)(gxb + 3) < (unsigned)Ww) { vd4.w = dcd[gy*Ww+gxb+3]; vc4.w = cd[gy*Ww+gxb+3]; }
            }
        }
        int lxb = seg * 4 - 1;   // lx of component 0
        if ((unsigned)(lxb + 0) < (unsigned)R3) s_qc[row][lxb + 0] = make_float2(vd4.x / (vc4.x + EPSF), vc4.x);
        if ((unsigned)(lxb + 1) < (unsigned)R3) s_qc[row][lxb + 1] = make_float2(vd4.y / (vc4.y + EPSF), vc4.y);
        if ((unsigned)(lxb + 2) < (unsigned)R3) s_qc[row][lxb + 2] = make_float2(vd4.z / (vc4.z + EPSF), vc4.z);
        if ((unsigned)(lxb + 3) < (unsigned)R3) s_qc[row][lxb + 3] = make_float2(vd4.w / (vc4.w + EPSF), vc4.w);
    }

    // ---- Prefetch cs/scs for Phase B (hide HBM latency under barrier) ----
    const int xB = tid % R2;          // 0..35
    const int tyB = tid / R2;         // active < 6 (216 threads)
    const int yb0 = tyB * 6;
    float pcs[6], pscs[6];
    if (tyB < 6) {
        int gx = tx0 - 2 + xB;
        bool colok = (unsigned)gx < (unsigned)Ww;
        #pragma unroll
        for (int j = 0; j < 6; ++j) {
            int gy = ty0 - 2 + yb0 + j;
            bool ok = colok && (unsigned)gy < (unsigned)Hh;
            int idx = ok ? (b * PLANE + gy * Ww + gx) : 0;
            pcs[j]  = ok ? cs[idx]  : 0.f;
            pscs[j] = ok ? scs[idx] : 0.f;
        }
    }
    __syncthreads();

    const float wps  = sw[18];
    const float wpow = sw[19];
    const float onemw = 1.f - wps;

    // ---- Phase B: stage 1, column sweep (36 cols x 6 groups of 6 rows) ----
    // Hierarchical first-wins argmax: row-max over dx (k-minor), combine over
    // dy (k-major) — exactly reproduces jnp.argmax first-occurrence order.
    if (tyB < 6) {
        float ma[3], md[3], mc[3];    // jmax row-partials (key, dq, c)
        float nv[3], nq[3];           // jmin row-partials (vc, dq+eps)
#define HROW_B(rr, slot) { \
        float2 q0 = s_qc[rr][xB]; float2 q1 = s_qc[rr][xB + 1]; float2 q2 = s_qc[rr][xB + 2]; \
        float a0 = q0.x * q0.y, a1 = q1.x * q1.y, a2 = q2.x * q2.y; \
        float A = a0, D = q0.x, C = q0.y; \
        if (a1 > A) { A = a1; D = q1.x; C = q1.y; } \
        if (a2 > A) { A = a2; D = q2.x; C = q2.y; } \
        ma[slot] = A; md[slot] = D; mc[slot] = C; \
        float V = q0.y, Q = q0.x + EPSF; \
        float e1 = q1.x + EPSF, e2 = q2.x + EPSF; \
        if (q1.y * Q > V * e1) { V = q1.y; Q = e1; } \
        if (q2.y * Q > V * e2) { V = q2.y; Q = e2; } \
        nv[slot] = V; nq[slot] = Q; }
        HROW_B(yb0 + 0, 0)
        HROW_B(yb0 + 1, 1)
        #pragma unroll
        for (int j = 0; j < 6; ++j) {
            const int sl2 = (j + 2) % 3, s0 = j % 3, s1 = (j + 1) % 3;
            HROW_B(yb0 + j + 2, sl2)
            float A = ma[s0], D = md[s0], C = mc[s0];
            if (ma[s1]  > A) { A = ma[s1];  D = md[s1];  C = mc[s1];  }
            if (ma[sl2] > A) { A = ma[sl2]; D = md[sl2]; C = mc[sl2]; }
            float V = nv[s0], Q = nq[s0];
            if (nv[s1]  * Q > V * nq[s1])  { V = nv[s1];  Q = nq[s1];  }
            if (nv[sl2] * Q > V * nq[sl2]) { V = nv[sl2]; Q = nq[sl2]; }
            const int yb = yb0 + j;
            const int gy = ty0 - 2 + yb, gx = tx0 - 2 + xB;
            float tc = 0.f, ts = 0.f;
            if ((unsigned)gy < (unsigned)Hh && (unsigned)gx < (unsigned)Ww) {
                float s_new = __builtin_amdgcn_exp2f(wpow *
                    (__builtin_amdgcn_logf(Q) - __builtin_amdgcn_logf(D + EPSF)));
                float cs_new = C * V;
                tc = pcs[j]  * wps + cs_new * onemw;
                ts = pscs[j] * wps + s_new * cs_new * onemw;
            }
            s_t[yb][xB] = make_float2(tc, ts);
        }
    }
    __syncthreads();

    // ---- Phase C: stage 2 conv, column sweep (34 cols x 7 groups of 5) ----
    // Results kept in registers; written to global later via aligned Phase D.
    const int xC = tid % R1;          // 0..33
    const int tyC = tid / R1;         // active < 7 (238 threads)
    const int yc0 = tyC * 5;
    float2 cres[5];
    if (tyC < 7) {
        const float wa0 = sw[9],  wb0 = sw[10];
        const float wa1 = sw[12], wb1 = sw[13];
        const float wa2 = sw[15], wb2 = sw[16];
        float2 u[3], tm[3];
#define HROW_C(rr, slot) { \
        float2 t0 = s_t[rr][xC]; float2 t1 = s_t[rr][xC + 1]; float2 t2 = s_t[rr][xC + 2]; \
        u[slot] = make_float2(t0.x + t2.x, t0.y + t2.y); tm[slot] = t1; }
        HROW_C(yc0 + 0, 0)
        HROW_C(yc0 + 1, 1)
        #pragma unroll
        for (int j = 0; j < 5; ++j) {
            const int yc = yc0 + j;
            if (yc < R1) {
                const int sl2 = (j + 2) % 3, s0 = j % 3, s1 = (j + 1) % 3;
                HROW_C(yc + 2, sl2)
                float accC = wa0 * u[s0].x + wb0 * tm[s0].x
                           + wa1 * u[s1].x + wb1 * tm[s1].x
                           + wa2 * u[sl2].x + wb2 * tm[sl2].x;
                float accS = wa0 * u[s0].y + wb0 * tm[s0].y
                           + wa1 * u[s1].y + wb1 * tm[s1].y
                           + wa2 * u[sl2].y + wb2 * tm[sl2].y;
                const int gy = ty0 - 1 + yc, gx = tx0 - 1 + xC;
                bool in_img = (unsigned)gy < (unsigned)Hh && (unsigned)gx < (unsigned)Ww;
                s_s[yc][xC] = in_img ? (accS * __builtin_amdgcn_rcpf(accC + EPSF)) : 0.f;
                cres[j] = make_float2(accC, accS);
            }
        }
    }
    __syncthreads();   // all s_t reads done; s_s ready

    // ---- Phase C2: dump conv results into dead s_t for aligned writes ----
    if (tyC < 7) {
        #pragma unroll
        for (int j = 0; j < 5; ++j) {
            const int yc = yc0 + j;
            if (yc < R1) s_t[yc][xC] = cres[j];
        }
    }
    __syncthreads();

    // ---- Phase D: stage 3 + ALL global writes (128B-aligned mapping) ----
    {
        const int xD = tid & 31, tyD = tid >> 5;
        const int yd0 = tyD * 4;
        float wdk[9];
        #pragma unroll
        for (int k = 0; k < 9; ++k) wdk[k] = sw[k];
        float  srw[3][3];
        float2 qrw[3][3];
#define HROW_D(rr, slot) { \
        srw[slot][0] = s_s[rr][xD]; srw[slot][1] = s_s[rr][xD + 1]; srw[slot][2] = s_s[rr][xD + 2]; \
        qrw[slot][0] = s_qc[rr + 2][xD + 2]; qrw[slot][1] = s_qc[rr + 2][xD + 3]; qrw[slot][2] = s_qc[rr + 2][xD + 4]; }
        HROW_D(yd0 + 0, 0)
        HROW_D(yd0 + 1, 1)
#define TAP_D(slot, kk, cc2) { \
        float wsk = ((kk) == 4) ? 1.f : (srw[slot][cc2] * sc); \
        float w = wdk[kk] * wsk; \
        float2 q = qrw[slot][cc2]; \
        acc_d += w * (q.x * (q.y + EPSF)); \
        acc_c += w * q.y; \
        acc_w += w; }
        #pragma unroll
        for (int j = 0; j < 4; ++j) {
            const int sl2 = (j + 2) % 3, s0 = j % 3, s1 = (j + 1) % 3;
            HROW_D(yd0 + j + 2, sl2)
            float sc = srw[s1][1];
            float acc_d = 0.f, acc_c = 0.f, acc_w = 0.f;
            TAP_D(s0, 0, 0) TAP_D(s0, 1, 1) TAP_D(s0, 2, 2)
            TAP_D(s1, 3, 0) TAP_D(s1, 4, 1) TAP_D(s1, 5, 2)
            TAP_D(sl2, 6, 0) TAP_D(sl2, 7, 1) TAP_D(sl2, 8, 2)
            float rinv = __builtin_amdgcn_rcpf(acc_w + EPSF);
            const int iy = yd0 + j;
            int idx = (ty0 + iy) * Ww + (tx0 + xD);
            float2 cv = s_t[iy + 1][xD + 1];   // (accC, accS) for this pixel
            out[(2 * b)     * PLANE + idx] = acc_d * rinv;   // x_out d-part
            out[(2 * b + 1) * PLANE + idx] = acc_c * rinv;   // x_out c-part
            out[(8 + b)     * PLANE + idx] = cv.y;           // scs_out
            out[(12 + b)    * PLANE + idx] = cv.x;           // cs_out
        }
    }
}

extern "C" void kernel_launch(void* const* d_in, const int* in_sizes, int n_in,
                              void* d_out, int out_size, void* d_ws, size_t ws_size,
                              hipStream_t stream) {
    const float* x        = (const float*)d_in[0];
    const float* scs      = (const float*)d_in[1];
    const float* cs       = (const float*)d_in[2];
    // d_in[3] = w_channel_d (1,1) -> normalizes to 1, unused
    const float* w_sp_d   = (const float*)d_in[4];
    const float* w_pow_s  = (const float*)d_in[5];
    const float* w_prop_s = (const float*)d_in[6];
    // d_in[7] = w_channel_s (1,1) -> normalizes to 1, unused
    const float* w_sp_s   = (const float*)d_in[8];
    float* out  = (float*)d_out;

    fused_all<<<dim3(24 * 24 * Bb), 256, 0, stream>>>(x, scs, cs, w_sp_d, w_sp_s,
                                                      w_pow_s, w_prop_s, out);
}